// Round 1
// baseline (405.524 us; speedup 1.0000x reference)
//
#include <hip/hip_runtime.h>

#define N_NODES 10000
#define N_EDGES 320000
#define N_CAND  100000
#define HID     256
#define N_MP    3
#define N_ATYPE 100

static __device__ __forceinline__ float relu_f(float x) { return x > 0.f ? x : 0.f; }

// ---------------------------------------------------------------------------
// C[M x 256] = act(A[M x 256] @ B[256 x 256] + bias)   (bias may be null)
// Tiles: BM=64, BN=64, BK=32; 256 threads; 4x4 per thread.
// ---------------------------------------------------------------------------
__global__ __launch_bounds__(256) void k_gemm(
    const float* __restrict__ A, const float* __restrict__ B,
    const float* __restrict__ bias, float* __restrict__ C,
    int M, int doRelu)
{
    const int K = 256;
    __shared__ float As[32][68];   // [k][m], stride 68 floats = 272B (16B aligned rows)
    __shared__ float Bs[32][64];   // [k][n]

    int tid = threadIdx.x;
    int tx = tid & 15;             // col group (4 cols each)
    int ty = tid >> 4;             // row group (4 rows each)
    int mb = blockIdx.x * 64;
    int nb = blockIdx.y * 64;

    int ar = tid >> 3;             // 0..31 (A row within half-tile)
    int ac = tid & 7;              // 0..7  (A k-chunk, 4 floats)
    int bc = tid & 15;             // 0..15 (B n-chunk, 4 floats)
    int brw = tid >> 4;            // 0..15 (B row within half-tile)

    float acc[4][4] = {};

    for (int k0 = 0; k0 < K; k0 += 32) {
        // A tile (64 x 32) -> As[k][m] (transposed store)
        #pragma unroll
        for (int h = 0; h < 2; ++h) {
            int row = mb + ar + h * 32;
            float4 av = make_float4(0.f, 0.f, 0.f, 0.f);
            if (row < M) av = *(const float4*)(A + (long)row * K + k0 + ac * 4);
            As[ac * 4 + 0][ar + h * 32] = av.x;
            As[ac * 4 + 1][ar + h * 32] = av.y;
            As[ac * 4 + 2][ar + h * 32] = av.z;
            As[ac * 4 + 3][ar + h * 32] = av.w;
        }
        // B tile (32 x 64) -> Bs[k][n]
        #pragma unroll
        for (int h = 0; h < 2; ++h) {
            int k = brw + h * 16;
            *(float4*)(&Bs[k][bc * 4]) =
                *(const float4*)(B + (long)(k0 + k) * 256 + nb + bc * 4);
        }
        __syncthreads();

        #pragma unroll
        for (int k = 0; k < 32; ++k) {
            float4 a4 = *(const float4*)(&As[k][ty * 4]);
            float4 b4 = *(const float4*)(&Bs[k][tx * 4]);
            float a[4] = {a4.x, a4.y, a4.z, a4.w};
            float b[4] = {b4.x, b4.y, b4.z, b4.w};
            #pragma unroll
            for (int i = 0; i < 4; ++i)
                #pragma unroll
                for (int j = 0; j < 4; ++j)
                    acc[i][j] = fmaf(a[i], b[j], acc[i][j]);
        }
        __syncthreads();
    }

    float bvv[4] = {0.f, 0.f, 0.f, 0.f};
    if (bias) {
        float4 bv = *(const float4*)(bias + nb + tx * 4);
        bvv[0] = bv.x; bvv[1] = bv.y; bvv[2] = bv.z; bvv[3] = bv.w;
    }
    #pragma unroll
    for (int i = 0; i < 4; ++i) {
        int row = mb + ty * 4 + i;
        if (row >= M) break;
        float r[4];
        #pragma unroll
        for (int j = 0; j < 4; ++j) {
            r[j] = acc[i][j] + bvv[j];
            if (doRelu) r[j] = relu_f(r[j]);
        }
        float4 st = make_float4(r[0], r[1], r[2], r[3]);
        *(float4*)(C + (long)row * 256 + nb + tx * 4) = st;
    }
}

// ---------------------------------------------------------------------------
// degree histogram
// ---------------------------------------------------------------------------
__global__ void k_hist(const int* __restrict__ ei,
                       int* __restrict__ dout, int* __restrict__ din)
{
    int e = blockIdx.x * blockDim.x + threadIdx.x;
    if (e >= N_EDGES) return;
    atomicAdd(&dout[ei[e]], 1);
    atomicAdd(&din[ei[N_EDGES + e]], 1);
}

__global__ void k_norm(const int* __restrict__ dout, const int* __restrict__ din,
                       float* __restrict__ ns, float* __restrict__ nd)
{
    int i = blockIdx.x * blockDim.x + threadIdx.x;
    if (i >= N_NODES) return;
    int o = dout[i], in = din[i];
    ns[i] = (o  > 0) ? (1.0f / sqrtf((float)o))  : 0.f;
    nd[i] = (in > 0) ? (1.0f / sqrtf((float)in)) : 0.f;
}

// h0[node][:] = E0[atom_types[node]][:]   (one wave per node, float4 per lane)
__global__ __launch_bounds__(256) void k_h0(const int* __restrict__ types,
                                            const float* __restrict__ E0,
                                            float* __restrict__ h)
{
    int node = blockIdx.x * 4 + (threadIdx.x >> 6);
    int lane = threadIdx.x & 63;
    if (node >= N_NODES) return;
    int t = types[node];
    ((float4*)h)[node * 64 + lane] = ((const float4*)E0)[t * 64 + lane];
}

// single-block exclusive scan -> row offsets (off[0]=0, off[i+1]=off[i]+deg[i])
__global__ __launch_bounds__(256) void k_scan(const int* __restrict__ deg,
                                              int* __restrict__ off, int n)
{
    __shared__ int part[256];
    int t = threadIdx.x;
    int chunk = (n + 255) / 256;
    int base = t * chunk;
    int s = 0;
    for (int i = 0; i < chunk; ++i) {
        int idx = base + i;
        if (idx < n) s += deg[idx];
    }
    part[t] = s;
    __syncthreads();
    for (int d = 1; d < 256; d <<= 1) {
        int v = (t >= d) ? part[t - d] : 0;
        __syncthreads();
        part[t] += v;
        __syncthreads();
    }
    int run = (t == 0) ? 0 : part[t - 1];
    if (t == 0) off[0] = 0;
    for (int i = 0; i < chunk; ++i) {
        int idx = base + i;
        if (idx < n) { run += deg[idx]; off[idx + 1] = run; }
    }
}

__global__ void k_fill(const int* __restrict__ ei, const int* __restrict__ off,
                       int* __restrict__ cur, int* __restrict__ csr)
{
    int e = blockIdx.x * blockDim.x + threadIdx.x;
    if (e >= N_EDGES) return;
    int d = ei[N_EDGES + e];
    int p = off[d] + atomicAdd(&cur[d], 1);
    csr[p] = ei[e];
}

// agg[n][:] = norm_dst[n] * sum_{e in in(n)} h[src(e)][:] * norm_src[src(e)]
__global__ __launch_bounds__(256) void k_agg(
    const float* __restrict__ h, const float* __restrict__ ns,
    const float* __restrict__ nd, const int* __restrict__ off,
    const int* __restrict__ csr, float* __restrict__ out)
{
    int node = blockIdx.x * 4 + (threadIdx.x >> 6);
    int lane = threadIdx.x & 63;
    if (node >= N_NODES) return;
    int s0 = off[node], s1 = off[node + 1];
    float4 acc = make_float4(0.f, 0.f, 0.f, 0.f);
    for (int e = s0; e < s1; ++e) {
        int s = csr[e];
        float w = ns[s];
        float4 hv = ((const float4*)h)[s * 64 + lane];
        acc.x = fmaf(hv.x, w, acc.x);
        acc.y = fmaf(hv.y, w, acc.y);
        acc.z = fmaf(hv.z, w, acc.z);
        acc.w = fmaf(hv.w, w, acc.w);
    }
    float d = nd[node];
    acc.x *= d; acc.y *= d; acc.z *= d; acc.w *= d;
    ((float4*)out)[node * 64 + lane] = acc;
}

// scores[c] = relu(P[u]+Q[v]+b1) . W2 + b2   (one wave per candidate)
__global__ __launch_bounds__(256) void k_score(
    const int* __restrict__ cand, const float* __restrict__ P,
    const float* __restrict__ Q, const float* __restrict__ b1,
    const float* __restrict__ W2, const float* __restrict__ b2,
    float* __restrict__ out)
{
    int c = blockIdx.x * 4 + (threadIdx.x >> 6);
    int lane = threadIdx.x & 63;
    if (c >= N_CAND) return;
    int u = cand[2 * c];
    int v = cand[2 * c + 1];
    float4 p = ((const float4*)P)[u * 64 + lane];
    float4 q = ((const float4*)Q)[v * 64 + lane];
    float4 b = ((const float4*)b1)[lane];
    float4 w = ((const float4*)W2)[lane];
    float hx = relu_f(p.x + q.x + b.x);
    float hy = relu_f(p.y + q.y + b.y);
    float hz = relu_f(p.z + q.z + b.z);
    float hw = relu_f(p.w + q.w + b.w);
    float d = hx * w.x + hy * w.y + hz * w.z + hw * w.w;
    #pragma unroll
    for (int o = 32; o > 0; o >>= 1)
        d += __shfl_xor(d, o, 64);
    if (lane == 0) out[c] = d + b2[0];
}

// ---------------------------------------------------------------------------
extern "C" void kernel_launch(void* const* d_in, const int* in_sizes, int n_in,
                              void* d_out, int out_size, void* d_ws, size_t ws_size,
                              hipStream_t stream)
{
    const int*   atom_types = (const int*)d_in[0];
    // d_in[1] bond_types: dead code in reference (e is deleted)
    const int*   edge_index = (const int*)d_in[2];
    const int*   candidates = (const int*)d_in[3];
    const float* atom_embed = (const float*)d_in[4];
    const float* atom_W     = (const float*)d_in[5];
    const float* atom_b     = (const float*)d_in[6];
    // d_in[7..9] bond params: unused
    const float* conv_W     = (const float*)d_in[10];
    const float* conv_b     = (const float*)d_in[11];
    const float* s_W1       = (const float*)d_in[12];
    const float* s_b1       = (const float*)d_in[13];
    const float* s_W2       = (const float*)d_in[14];
    const float* s_b2       = (const float*)d_in[15];
    float* out = (float*)d_out;

    char* w = (char*)d_ws;
    size_t o = 0;
    auto alloc = [&](size_t bytes) {
        void* p = w + o;
        o += (bytes + 255) & ~(size_t)255;
        return p;
    };
    float* h0  = (float*)alloc((size_t)N_NODES * HID * 4);
    float* h1  = (float*)alloc((size_t)N_NODES * HID * 4);
    float* agg = (float*)alloc((size_t)N_NODES * HID * 4);
    float* E0  = (float*)alloc((size_t)N_ATYPE * HID * 4);
    int*   ints = (int*)alloc((size_t)3 * N_NODES * 4);   // dego | degi | cursor
    float* ns  = (float*)alloc((size_t)N_NODES * 4);
    float* nd  = (float*)alloc((size_t)N_NODES * 4);
    int*   off = (int*)alloc((size_t)(N_NODES + 1) * 4);
    int*   csr = (int*)alloc((size_t)N_EDGES * 4);
    int* dego = ints;
    int* degi = ints + N_NODES;
    int* cur  = ints + 2 * N_NODES;

    hipMemsetAsync(ints, 0, (size_t)3 * N_NODES * 4, stream);

    // E0 = atom_embed @ atom_W + atom_b   (100 x 256)
    k_gemm<<<dim3(2, 4), 256, 0, stream>>>(atom_embed, atom_W, atom_b, E0, N_ATYPE, 0);

    k_hist<<<(N_EDGES + 255) / 256, 256, 0, stream>>>(edge_index, dego, degi);
    k_norm<<<(N_NODES + 255) / 256, 256, 0, stream>>>(dego, degi, ns, nd);
    k_h0<<<N_NODES / 4, 256, 0, stream>>>(atom_types, E0, h0);
    k_scan<<<1, 256, 0, stream>>>(degi, off, N_NODES);
    k_fill<<<(N_EDGES + 255) / 256, 256, 0, stream>>>(edge_index, off, cur, csr);

    const float* hc = h0;
    float* hn = h1;
    for (int i = 0; i < N_MP; ++i) {
        k_agg<<<N_NODES / 4, 256, 0, stream>>>(hc, ns, nd, off, csr, agg);
        k_gemm<<<dim3((N_NODES + 63) / 64, 4), 256, 0, stream>>>(
            agg, conv_W + (size_t)i * HID * HID, conv_b + (size_t)i * HID, hn, N_NODES, 1);
        float* t = (float*)hc; hc = hn; hn = t;
    }
    // after 3 layers: hc == h1, hn == h0. Reuse agg as P, h0 as Q.
    float* P = agg;
    float* Q = hn;
    k_gemm<<<dim3((N_NODES + 63) / 64, 4), 256, 0, stream>>>(hc, s_W1, nullptr, P, N_NODES, 0);
    k_gemm<<<dim3((N_NODES + 63) / 64, 4), 256, 0, stream>>>(hc, s_W1 + HID * HID, nullptr, Q, N_NODES, 0);

    k_score<<<N_CAND / 4, 256, 0, stream>>>(candidates, P, Q, s_b1, s_W2, s_b2, out);
}